// Round 11
// baseline (89.368 us; speedup 1.0000x reference)
//
#include <hip/hip_runtime.h>
#include <hip/hip_bf16.h>

// Problem constants: B=128, C=21, L=2048, W=32, S=8, O=16, NW=252, NK=4032, K=672
#define Bb   128
#define Cc   21
#define Ll   2048
#define Ss   8
#define Oo   16
#define NWw  252
#define NKk  4032
#define Kk   672
#define XP   96    // LDS row pitch for 88-col x patch (12 x 16B granules)

typedef __attribute__((ext_vector_type(8))) short  short8;  // 8 bf16 = 4 VGPRs
typedef __attribute__((ext_vector_type(4))) float  f32x4;

static __device__ __forceinline__ unsigned short f2bf(float f) {
    union { __hip_bfloat16 h; unsigned short u; } cv;
    cv.h = __float2bfloat16(f);
    return cv.u;
}

static __device__ __forceinline__ short8 cvt8(const float4 a0, const float4 a1) {
    short8 a;
    a[0] = (short)f2bf(a0.x); a[1] = (short)f2bf(a0.y);
    a[2] = (short)f2bf(a0.z); a[3] = (short)f2bf(a0.w);
    a[4] = (short)f2bf(a1.x); a[5] = (short)f2bf(a1.y);
    a[6] = (short)f2bf(a1.z); a[7] = (short)f2bf(a1.w);
    return a;
}

// R8's 27 us kernel time == 79 MB FETCH / 2.7 TB/s cold-read rate: the cost
// is BYTES, and x is fetched ~3x (straddle + failed cross-window L2 reuse).
// Flip the blocking so each x byte is staged ONCE per block:
//   block = (XCD r=bid%8, batch-tile bt: 16 batches, window-group g: 8 windows)
//   - stage x patch 16b x 21c x 88cols (union of the group's windows; 352-B
//     sequential runs, 16B-aligned) -> 63 KB bf16 LDS. x total read ~1.09x.
//   - one barrier; then each of 4 waves computes 2 windows (16b x 16o, K=672):
//     A-frags from LDS, B-frags per-wave from global w fp32 (8x demand per
//     XCD; the 1.35 MB w slab is L2-shareable across the XCD's 32 blocks).
//   - window j=251 (s=2016) is inside group r=7,g=3's clamped patch.
__global__ __launch_bounds__(256, 2)
void fb_fwd(const float* __restrict__ x, const float* __restrict__ w,
            float* __restrict__ out) {
    __shared__ unsigned short xs[16 * Cc * XP];   // 63 KB

    const int bid = blockIdx.x;
    const int r   = bid & 7;          // XCD id (dispatch heuristic, R4+)
    const int t   = bid >> 3;         // 0..31 within XCD
    const int bt  = t & 7;            // batch tile: rows [16bt, 16bt+16)
    const int g   = t >> 3;           // window subgroup 0..3
    const int jb  = r * 32 + g * 8;   // first window of group
    const int c_lo = r * 256 + g * 64;                   // patch col start
    const int c_hi = (c_lo + 88 < Ll) ? c_lo + 88 : Ll;  // clamped end
    const int tid  = threadIdx.x;

    // ---- stage x patch: 336 (b,c) rows x 22 float4, fp32 -> bf16 LDS ----
    for (int i = tid; i < 336 * 22; i += 256) {
        const int row = i / 22;               // bi*21 + ci  (const-div)
        const int f4  = i - row * 22;
        const int col = c_lo + f4 * 4;
        if (col < c_hi) {
            const float4 v =
                *(const float4*)(x + ((size_t)(bt * 336 + row)) * Ll + col);
            *(ushort4*)&xs[row * XP + f4 * 4] =
                make_ushort4(f2bf(v.x), f2bf(v.y), f2bf(v.z), f2bf(v.w));
        }
    }
    __syncthreads();

    const int lane = tid & 63;
    const int wv   = tid >> 6;       // 0..3
    const int col  = lane & 15;      // A m-row (batch within tile) / B n (=o)
    const int quad = lane >> 4;      // k-chunk selector

    for (int wloc = 0; wloc < 2; ++wloc) {
        const int j = jb + wv * 2 + wloc;
        if (j >= NWw) continue;                        // wave-uniform skip
        const int s    = (j < NWw - 1) ? j * Ss : (Ll - 32);
        const int soff = s - c_lo;                     // 0..56, mult of 8

        const float* wp = w + (size_t)j * Oo * Kk + (size_t)col * Kk + quad * 8;
        const unsigned short* ap = &xs[col * (Cc * XP) + soff + quad * 8];

        f32x4 acc = {0.f, 0.f, 0.f, 0.f};
#pragma unroll
        for (int cc = 0; cc < Cc; ++cc) {
            const float4 b0 = *(const float4*)(wp + cc * 32);
            const float4 b1 = *(const float4*)(wp + cc * 32 + 4);
            const short8 a  = *(const short8*)(ap + cc * XP);
            acc = __builtin_amdgcn_mfma_f32_16x16x32_bf16(
                a, cvt8(b0, b1), acc, 0, 0, 0);
        }

        // C/D layout: col = lane&15 (=o), row = quad*4 + reg (=batch)
        float* op = out + (size_t)(bt * 16 + quad * 4) * NKk + j * 16 + col;
#pragma unroll
        for (int rr = 0; rr < 4; ++rr)
            op[(size_t)rr * NKk] = acc[rr];
    }
}

extern "C" void kernel_launch(void* const* d_in, const int* in_sizes, int n_in,
                              void* d_out, int out_size, void* d_ws, size_t ws_size,
                              hipStream_t stream) {
    const float* x = (const float*)d_in[0];   // (128, 21, 2048) fp32
    const float* w = (const float*)d_in[1];   // (4032, 672) fp32
    float* out = (float*)d_out;               // (128, 4032) fp32
    fb_fwd<<<dim3(256), dim3(256), 0, stream>>>(x, w, out);
}

// Round 12
// 82.698 us; speedup vs baseline: 1.0807x; 1.0807x over previous
//
#include <hip/hip_runtime.h>
#include <hip/hip_bf16.h>

// Problem constants: B=128, C=21, L=2048, W=32, S=8, O=16, NW=252, NK=4032, K=672
#define Bb   128
#define Cc   21
#define Ll   2048
#define Ss   8
#define Oo   16
#define NWw  252
#define NKk  4032
#define Kk   672
#define KP   680   // LDS pitch (bf16): 85 x 16B granules/row, conflict-light b128

typedef __attribute__((ext_vector_type(8))) short  short8;  // 8 bf16 = 4 VGPRs
typedef __attribute__((ext_vector_type(4))) float  f32x4;

static __device__ __forceinline__ unsigned short f2bf(float f) {
    union { __hip_bfloat16 h; unsigned short u; } cv;
    cv.h = __float2bfloat16(f);
    return cv.u;
}

static __device__ __forceinline__ short8 cvt8(const float4 a0, const float4 a1) {
    short8 a;
    a[0] = (short)f2bf(a0.x); a[1] = (short)f2bf(a0.y);
    a[2] = (short)f2bf(a0.z); a[3] = (short)f2bf(a0.w);
    a[4] = (short)f2bf(a1.x); a[5] = (short)f2bf(a1.y);
    a[6] = (short)f2bf(a1.z); a[7] = (short)f2bf(a1.w);
    return a;
}

// R8 = session optimum (83.7 us total, kernel ~26 us), reinstalled after
// R9 (L2 warm pass: +10, cross-dispatch L2 reuse doesn't exist),
// R10 (physical transpose: +3, 2x write amplification on scattered stores),
// R11 (batch-tile x window-group re-block: +6, redundant per-wave w reads).
// Structure:
//  - single dispatch, compulsory bytes only (x 22 + w 10.8 + out 2 = 35 MB);
//  - grid 256 (252 windows + 4 idle), XCD r=bid%8 owns windows [32r,32r+32)
//    -> 3.1 MB fp32 x-slab per XCD reused within-kernel in L2 (R4's win);
//  - 512 thr = 8 waves x 16-batch m-tiles = all 128 batches; w staged ONCE
//    per window fp32->bf16 into LDS (R7: per-wave B redundancy costs ~4 us);
//  - whole A-slice batch-issued before the single barrier (21 float4-pairs
//    in flight), cvt'd in-register, then a pure 21-MFMA sweep.
__global__ __launch_bounds__(512)
void fb_fwd(const float* __restrict__ x, const float* __restrict__ w,
            float* __restrict__ out) {
    __shared__ unsigned short ws[Oo * KP];   // 21.8 KB

    const int bid = blockIdx.x;
    const int j   = (bid & 7) * 32 + (bid >> 3);          // XCD-grouped window
    if (j >= NWw) return;                                  // 4 tail blocks idle
    const int s    = (j < NWw - 1) ? j * Ss : (Ll - 32);  // STARTS[j], mult of 8
    const int tid  = threadIdx.x;
    const int lane = tid & 63;
    const int wv   = tid >> 6;       // 0..7: m-tile id (16 batch rows)
    const int col  = lane & 15;      // MFMA m-row (A) / n-col (B = w-row o)
    const int quad = lane >> 4;      // k-chunk selector

    // ---- batch-issue the whole A-slice (21 x 32 B fp32, all in flight) ----
    const float* xrow = x + ((size_t)(wv * 16 + col) * Cc) * Ll + s + quad * 8;
    float4 a0[Cc], a1[Cc];
#pragma unroll
    for (int c = 0; c < Cc; ++c) {
        a0[c] = *(const float4*)(xrow + (size_t)c * Ll);
        a1[c] = *(const float4*)(xrow + (size_t)c * Ll + 4);
    }

    // ---- stage weight[j]: 16 x 672 fp32 -> bf16 LDS, [o][k] (B^T) ----
    {
        const float4* wj4 = (const float4*)(w + (size_t)j * Oo * Kk);
        for (int t = tid; t < Oo * (Kk / 4); t += 512) {   // 2688 float4
            float4 v = wj4[t];
            int o = t / (Kk / 4);                           // Kk/4 = 168
            int r = t - o * (Kk / 4);
            *(ushort4*)&ws[o * KP + r * 4] =
                make_ushort4(f2bf(v.x), f2bf(v.y), f2bf(v.z), f2bf(v.w));
        }
    }

    // cvt A to bf16 frags while the stage drains
    short8 afr[Cc];
#pragma unroll
    for (int c = 0; c < Cc; ++c) afr[c] = cvt8(a0[c], a1[c]);

    __syncthreads();

    const unsigned short* wrow = &ws[col * KP + quad * 8];
    f32x4 acc = {0.f, 0.f, 0.f, 0.f};
#pragma unroll
    for (int c = 0; c < Cc; ++c)
        acc = __builtin_amdgcn_mfma_f32_16x16x32_bf16(
            afr[c], *(const short8*)(wrow + c * 32), acc, 0, 0, 0);

    // ---- C/D layout: col = lane&15, row = quad*4 + reg ----
    const int rbase = wv * 16 + quad * 4;
    float* op = out + (size_t)rbase * NKk + j * 16 + col;
#pragma unroll
    for (int r = 0; r < 4; ++r)
        op[(size_t)r * NKk] = acc[r];
}

extern "C" void kernel_launch(void* const* d_in, const int* in_sizes, int n_in,
                              void* d_out, int out_size, void* d_ws, size_t ws_size,
                              hipStream_t stream) {
    const float* x = (const float*)d_in[0];   // (128, 21, 2048) fp32
    const float* w = (const float*)d_in[1];   // (4032, 672) fp32
    float* out = (float*)d_out;               // (128, 4032) fp32
    fb_fwd<<<dim3(256), dim3(512), 0, stream>>>(x, w, out);
}